// Round 11
// baseline (319.394 us; speedup 1.0000x reference)
//
#include <hip/hip_runtime.h>
#include <hip/hip_fp16.h>
#include <math.h>

#define WAVE 64
#define NEG_SLOPE 0.2f
#define LSTR 68   // padded LDS row stride (dwords)
#define CHUNK 8192

// ---------------------------------------------------------------------------
// CSR build: atomic-free two-level counting sort.
// count writes per-chunk bucket partials part[c][b]; scan turns them into
// chunk-prefix offsets + global bucket offsets; place writes (src,dst) pairs
// in per-bucket bursts; build makes the exact per-node CSR in LDS.
// ---------------------------------------------------------------------------

// K1: blocks [0,nchunk) = bucket partial counts; blocks [nchunk,..) = gemm0.
__global__ __launch_bounds__(256) void count_gemm0_kernel(
    const int* __restrict__ dst, int* __restrict__ part, int e, int nb, int nchunk,
    const float* __restrict__ X, const float* __restrict__ W,
    const float* __restrict__ a_s, const float* __restrict__ a_d,
    __half* __restrict__ H, float* __restrict__ S, float* __restrict__ D, int n) {
    __shared__ float Xs[64 * LSTR];
    __shared__ float Ws[64 * LSTR];
    int t = threadIdx.x;

    if (blockIdx.x < nchunk) {
        // ---- bucket partial counts (hist in Ws storage) ----
        int* cnt = (int*)Ws;
        for (int b = t; b < nb; b += 256) cnt[b] = 0;
        __syncthreads();
        int base = blockIdx.x * CHUNK;
#pragma unroll
        for (int k = 0; k < CHUNK / 256; ++k) {
            int i = base + k * 256 + t;
            if (i < e) atomicAdd(&cnt[dst[i] >> 7], 1);
        }
        __syncthreads();
        for (int b = t; b < nb; b += 256)
            part[(size_t)blockIdx.x * nb + b] = cnt[b];
        return;
    }

    // ---- gemm0: H(fp16) = X @ W (K=128); S,D logits ----
    constexpr int K = 128;
    int tx = t & 15;
    int ty = t >> 4;
    int base = (blockIdx.x - nchunk) * 64;
    float acc[4][4] = {};
    int q = t & 3;
    int srow = t >> 2;

    for (int k0 = 0; k0 < K; k0 += 64) {
        int grow = base + srow;
#pragma unroll
        for (int j = 0; j < 4; ++j) {
            int c = 16 * j + 4 * q;
            float4 v = make_float4(0.f, 0.f, 0.f, 0.f);
            if (grow < n) v = *(const float4*)(X + (size_t)grow * K + k0 + c);
            *(float4*)(Xs + srow * LSTR + c) = v;
            float4 w = *(const float4*)(W + (size_t)(k0 + srow) * 64 + c);
            *(float4*)(Ws + srow * LSTR + c) = w;
        }
        __syncthreads();
#pragma unroll 8
        for (int kk = 0; kk < 64; ++kk) {
            float4 wv = *(const float4*)(Ws + kk * LSTR + 4 * tx);
#pragma unroll
            for (int i = 0; i < 4; ++i) {
                float xv = Xs[(4 * ty + i) * LSTR + kk];
                acc[i][0] = fmaf(xv, wv.x, acc[i][0]);
                acc[i][1] = fmaf(xv, wv.y, acc[i][1]);
                acc[i][2] = fmaf(xv, wv.z, acc[i][2]);
                acc[i][3] = fmaf(xv, wv.w, acc[i][3]);
            }
        }
        __syncthreads();
    }

    const float4 av_s = *(const float4*)(a_s + 4 * tx);
    const float4 av_d = *(const float4*)(a_d + 4 * tx);
#pragma unroll
    for (int i = 0; i < 4; ++i) {
        int row = base + 4 * ty + i;
        bool ok = row < n;
        if (ok) {
            __half2 h01 = __floats2half2_rn(acc[i][0], acc[i][1]);
            __half2 h23 = __floats2half2_rn(acc[i][2], acc[i][3]);
            uint2 u;
            u.x = *(unsigned int*)&h01;
            u.y = *(unsigned int*)&h23;
            *(uint2*)(H + (size_t)row * 64 + 4 * tx) = u;
        }
        float ps = acc[i][0] * av_s.x + acc[i][1] * av_s.y +
                   acc[i][2] * av_s.z + acc[i][3] * av_s.w;
        float pd = acc[i][0] * av_d.x + acc[i][1] * av_d.y +
                   acc[i][2] * av_d.z + acc[i][3] * av_d.w;
        for (int o = 1; o < 16; o <<= 1) {
            ps += __shfl_xor(ps, o);
            pd += __shfl_xor(pd, o);
        }
        if (tx == 0 && ok) { S[row] = ps; D[row] = pd; }
    }
}

// K2: one block. part[c][b] -> intra-bucket chunk prefix (in place);
// bucket totals -> exclusive boff; totals.
__global__ __launch_bounds__(512) void bucket_scan_kernel(
    int* __restrict__ part, int* __restrict__ boff, int* __restrict__ rowptr,
    int nchunk, int nb, int e, int n) {
    __shared__ int sh[512];
    int t = threadIdx.x;
    int total = 0;
    if (t < nb) {
        int run = 0;
        for (int c = 0; c < nchunk; ++c) {
            size_t idx = (size_t)c * nb + t;
            int v = part[idx];
            part[idx] = run;
            run += v;
        }
        total = run;
    }
    sh[t] = total;
    __syncthreads();
    for (int o = 1; o < 512; o <<= 1) {
        int u = (t >= o) ? sh[t - o] : 0;
        __syncthreads();
        sh[t] += u;
        __syncthreads();
    }
    if (t < nb) boff[t] = sh[t] - total;
    if (t == 0) { boff[nb] = e; rowptr[n] = e + n; }
}

// K3: binned placement, no global atomics (bases from boff + part prefix).
__global__ __launch_bounds__(256) void bucket_place_kernel(
    const int* __restrict__ src, const int* __restrict__ dst,
    const int* __restrict__ part, const int* __restrict__ boff,
    int2* __restrict__ binned, int e, int nb) {
    extern __shared__ int lds[];
    int* cnt = lds;        // [nb]
    int* bas = lds + nb;   // [nb]
    int t = threadIdx.x;
    for (int b = t; b < nb; b += 256) cnt[b] = 0;
    __syncthreads();
    int base = blockIdx.x * CHUNK;
#pragma unroll
    for (int k = 0; k < CHUNK / 256; ++k) {
        int i = base + k * 256 + t;
        if (i < e) atomicAdd(&cnt[dst[i] >> 7], 1);
    }
    __syncthreads();
    for (int b = t; b < nb; b += 256) {
        bas[b] = boff[b] + part[(size_t)blockIdx.x * nb + b];
        cnt[b] = 0;
    }
    __syncthreads();
#pragma unroll
    for (int k = 0; k < CHUNK / 256; ++k) {
        int i = base + k * 256 + t;
        if (i < e) {
            int d = dst[i];
            int bk = d >> 7;
            int r = atomicAdd(&cnt[bk], 1);
            binned[bas[bk] + r] = make_int2(src[i], d);
        }
    }
}

// K4: one block per bucket -> exact per-node CSR. Self loop at slot 0.
__global__ __launch_bounds__(256) void bucket_build_kernel(
    const int2* __restrict__ binned, const int* __restrict__ boff,
    int* __restrict__ csr_src, int* __restrict__ rowptr, int n) {
    __shared__ int cnt[128], off[128], pcnt[128];
    int b = blockIdx.x;
    int t = threadIdx.x;
    int nodeBase = b << 7;
    int nc = min(128, n - nodeBase);
    int e0 = boff[b], e1 = boff[b + 1];
    int ne = e1 - e0;
    if (t < 128) { cnt[t] = 1; pcnt[t] = 1; }  // self-loop reserves slot 0
    __syncthreads();
    for (int i = t; i < ne; i += 256)
        atomicAdd(&cnt[binned[e0 + i].y - nodeBase], 1);
    __syncthreads();
    if (t < 128) off[t] = cnt[t];
    __syncthreads();
    for (int o = 1; o < 128; o <<= 1) {
        int u = (t >= o && t < 128) ? off[t - o] : 0;
        __syncthreads();
        if (t < 128) off[t] += u;
        __syncthreads();
    }
    if (t < 128) off[t] -= cnt[t];  // exclusive
    __syncthreads();
    int csrBase = e0 + nodeBase;
    if (t < nc) {
        rowptr[nodeBase + t] = csrBase + off[t];
        csr_src[csrBase + off[t]] = nodeBase + t;  // self loop
    }
    for (int i = t; i < ne; i += 256) {
        int2 p = binned[e0 + i];
        int loc = p.y - nodeBase;
        int r = atomicAdd(&pcnt[loc], 1);
        csr_src[csrBase + off[loc] + r] = p.x;
    }
}

// ---------------------------------------------------------------------------
// Device helper: full-wave GAT aggregation for ONE dst node (fp16 H).
// Returns normalized+bias(+relu) float4 valid on eg==0 lanes.
// ---------------------------------------------------------------------------
__device__ __forceinline__ float4 gat_node16(
    const __half* __restrict__ H, const float* __restrict__ S,
    const int* __restrict__ rowptr, const int* __restrict__ csr_src,
    const float* __restrict__ D, const float4 bv, int wid, int lane,
    int do_relu) {
    int eg = lane >> 4;
    int cg = lane & 15;
    int start = rowptr[wid];
    int end   = rowptr[wid + 1];
    float d_i = D[wid];

    float z = 0.f;
    float4 acc = make_float4(0.f, 0.f, 0.f, 0.f);

    for (int cb = start; cb < end; cb += WAVE) {
        int j = cb + lane;
        bool v = j < end;
        int sc = v ? csr_src[j] : 0;
        float sv = S[sc];
        float e = sv + d_i;
        e = (e > 0.f) ? e : NEG_SLOPE * e;
        float w = v ? __expf(e) : 0.f;

        int nch = min(WAVE, end - cb);
        int rounds = (nch + 3) >> 2;
#pragma unroll 4
        for (int r = 0; r < rounds; ++r) {
            int idx = 4 * r + eg;
            float wr = __shfl(w, idx);
            int   sr = __shfl(sc, idx);
            float2 f0 = make_float2(0.f, 0.f), f1 = f0;
            if (idx < nch) {
                uint2 u = *(const uint2*)(H + (size_t)sr * 64 + 4 * cg);
                f0 = __half22float2(*(__half2*)&u.x);
                f1 = __half22float2(*(__half2*)&u.y);
            }
            z += wr;
            acc.x = fmaf(wr, f0.x, acc.x);
            acc.y = fmaf(wr, f0.y, acc.y);
            acc.z = fmaf(wr, f1.x, acc.z);
            acc.w = fmaf(wr, f1.y, acc.w);
        }
    }

    for (int o = 16; o < 64; o <<= 1) {
        acc.x += __shfl_xor(acc.x, o);
        acc.y += __shfl_xor(acc.y, o);
        acc.z += __shfl_xor(acc.z, o);
        acc.w += __shfl_xor(acc.w, o);
        z     += __shfl_xor(z, o);
    }

    float inv = 1.f / (z + 1e-16f);
    float4 o4;
    o4.x = acc.x * inv + bv.x;
    o4.y = acc.y * inv + bv.y;
    o4.z = acc.z * inv + bv.z;
    o4.w = acc.w * inv + bv.w;
    if (do_relu) {
        o4.x = fmaxf(o4.x, 0.f); o4.y = fmaxf(o4.y, 0.f);
        o4.z = fmaxf(o4.z, 0.f); o4.w = fmaxf(o4.w, 0.f);
    }
    return o4;
}

// ---------------------------------------------------------------------------
// Fused agg(layer l) + gemm(layer l+1), 1024-thread blocks (16 waves).
// Phase A: each wave aggregates 4 of the tile's 64 nodes -> Xs (LDS only;
// the fp32 inter-layer activation never touches global). Full agg TLP:
// 782 blocks x 16 waves = 12512 node-waves (R9's failure had 4/block).
// Phase B: gemm K=64 from Xs; W via L1 broadcast (16KB, hot) - no Ws tile,
// LDS stays 17.4KB -> 2 blocks/CU = 32 waves/CU.
// Phase C: fp16 H store + S/D logit reduction.
// ---------------------------------------------------------------------------
__global__ __launch_bounds__(1024, 8) void agg_gemm_kernel(
    const __half* __restrict__ Hin, const float* __restrict__ Sin,
    const float* __restrict__ Din, const int* __restrict__ rowptr,
    const int* __restrict__ csr_src, const float* __restrict__ bias,
    const float* __restrict__ W, const float* __restrict__ a_s,
    const float* __restrict__ a_d, __half* __restrict__ Hout,
    float* __restrict__ Sout, float* __restrict__ Dout, int n) {
    __shared__ float Xs[64 * LSTR];
    int t = threadIdx.x;
    int lane = t & 63;
    int wv = t >> 6;        // wave 0..15
    int base = blockIdx.x * 64;
    int eg = lane >> 4;
    int cg = lane & 15;
    const float4 bv = *(const float4*)(bias + 4 * cg);

    // Phase A: 4 nodes per wave
#pragma unroll
    for (int k = 0; k < 4; ++k) {
        int local = 4 * wv + k;
        int wid = base + local;
        if (wid < n) {
            float4 o4 = gat_node16(Hin, Sin, rowptr, csr_src, Din, bv, wid, lane, 1);
            if (eg == 0) *(float4*)(Xs + local * LSTR + 4 * cg) = o4;
        } else if (eg == 0) {
            *(float4*)(Xs + local * LSTR + 4 * cg) = make_float4(0.f, 0.f, 0.f, 0.f);
        }
    }
    __syncthreads();

    // Phase B: gemm K=64; thread = (row 0..63, colq 0..15)
    int row = t >> 4;
    int txq = t & 15;
    float a0 = 0.f, a1 = 0.f, a2 = 0.f, a3 = 0.f;
#pragma unroll 8
    for (int kk = 0; kk < 64; ++kk) {
        float xv = Xs[row * LSTR + kk];               // 16-lane broadcast
        float4 wv4 = *(const float4*)(W + kk * 64 + 4 * txq);  // L1-hot
        a0 = fmaf(xv, wv4.x, a0);
        a1 = fmaf(xv, wv4.y, a1);
        a2 = fmaf(xv, wv4.z, a2);
        a3 = fmaf(xv, wv4.w, a3);
    }

    // Phase C: epilogue
    int grow = base + row;
    bool ok = grow < n;
    if (ok) {
        __half2 h01 = __floats2half2_rn(a0, a1);
        __half2 h23 = __floats2half2_rn(a2, a3);
        uint2 u;
        u.x = *(unsigned int*)&h01;
        u.y = *(unsigned int*)&h23;
        *(uint2*)(Hout + (size_t)grow * 64 + 4 * txq) = u;
    }
    const float4 av_s = *(const float4*)(a_s + 4 * txq);
    const float4 av_d = *(const float4*)(a_d + 4 * txq);
    float ps = a0 * av_s.x + a1 * av_s.y + a2 * av_s.z + a3 * av_s.w;
    float pd = a0 * av_d.x + a1 * av_d.y + a2 * av_d.z + a3 * av_d.w;
    for (int o = 1; o < 16; o <<= 1) {
        ps += __shfl_xor(ps, o);
        pd += __shfl_xor(pd, o);
    }
    if (txq == 0 && ok) { Sout[grow] = ps; Dout[grow] = pd; }
}

// ---------------------------------------------------------------------------
// Final standalone aggregation (layer 2, no relu) -> d_out.
// ---------------------------------------------------------------------------
__global__ __launch_bounds__(256) void gat_aggregate_kernel(
    const __half* __restrict__ H, const float* __restrict__ S,
    const float* __restrict__ D, const int* __restrict__ rowptr,
    const int* __restrict__ csr_src, const float* __restrict__ bias,
    float* __restrict__ OUT, int n) {
    int wid  = (blockIdx.x * blockDim.x + threadIdx.x) >> 6;
    int lane = threadIdx.x & 63;
    if (wid >= n) return;
    int eg = lane >> 4;
    int cg = lane & 15;
    const float4 bv = *(const float4*)(bias + 4 * cg);
    float4 o4 = gat_node16(H, S, rowptr, csr_src, D, bv, wid, lane, 0);
    if (eg == 0) *(float4*)(OUT + (size_t)wid * 64 + 4 * cg) = o4;
}

// ---------------------------------------------------------------------------

static inline size_t align256(size_t x) { return (x + 255) & ~(size_t)255; }

extern "C" void kernel_launch(void* const* d_in, const int* in_sizes, int n_in,
                              void* d_out, int out_size, void* d_ws, size_t ws_size,
                              hipStream_t stream) {
    const float* x    = (const float*)d_in[0];
    const int*   esrc = (const int*)d_in[1];
    const int*   edst = (const int*)d_in[2];
    const int E = in_sizes[1];
    const int N = in_sizes[0] / 128;

    const float* W0 = (const float*)d_in[3];
    const float* as0 = (const float*)d_in[4];
    const float* ad0 = (const float*)d_in[5];
    const float* b0 = (const float*)d_in[6];
    const float* W1 = (const float*)d_in[7];
    const float* as1 = (const float*)d_in[8];
    const float* ad1 = (const float*)d_in[9];
    const float* b1 = (const float*)d_in[10];
    const float* W2 = (const float*)d_in[11];
    const float* as2 = (const float*)d_in[12];
    const float* ad2 = (const float*)d_in[13];
    const float* b2 = (const float*)d_in[14];

    const int NB = (N + 127) >> 7;               // buckets (<=512 for scan)
    const int nchunk = (E + CHUNK - 1) / CHUNK;  // <=512 assumed (98 here)

    // workspace layout
    char* p = (char*)d_ws;
    int* part    = (int*)p; p += align256((size_t)nchunk * NB * 4);
    int* boff    = (int*)p; p += align256((size_t)(NB + 1) * 4);
    int* rowptr  = (int*)p; p += align256((size_t)(N + 1) * 4);
    int* csr_src = (int*)p; p += align256((size_t)(E + N) * 4);
    int2* binned = (int2*)p; p += align256((size_t)E * 8);
    __half* hA = (__half*)p; p += align256((size_t)N * 64 * 2);
    __half* hB = (__half*)p; p += align256((size_t)N * 64 * 2);
    float* sA = (float*)p; p += align256((size_t)N * 4);
    float* dA = (float*)p; p += align256((size_t)N * 4);
    float* sB = (float*)p; p += align256((size_t)N * 4);
    float* dB = (float*)p; p += align256((size_t)N * 4);
    float* out = (float*)d_out;

    int tile_grid = (N + 63) / 64;
    int agg_grid  = (N + 3) / 4;

    // K1: bucket partial counts (atomic-free global) || gemm0 -> hA,sA,dA
    count_gemm0_kernel<<<nchunk + tile_grid, 256, 0, stream>>>(
        edst, part, E, NB, nchunk, x, W0, as0, ad0, hA, sA, dA, N);
    // K2..K4: CSR
    bucket_scan_kernel<<<1, 512, 0, stream>>>(part, boff, rowptr, nchunk, NB, E, N);
    bucket_place_kernel<<<nchunk, 256, 2 * NB * 4, stream>>>(esrc, edst, part, boff, binned, E, NB);
    bucket_build_kernel<<<NB, 256, 0, stream>>>(binned, boff, csr_src, rowptr, N);
    // K5: agg L0 (relu,b0) + gemm L1 -> hB,sB,dB
    agg_gemm_kernel<<<tile_grid, 1024, 0, stream>>>(hA, sA, dA, rowptr, csr_src, b0,
                                                    W1, as1, ad1, hB, sB, dB, N);
    // K6: agg L1 (relu,b1) + gemm L2 -> hA,sA,dA
    agg_gemm_kernel<<<tile_grid, 1024, 0, stream>>>(hB, sB, dB, rowptr, csr_src, b1,
                                                    W2, as2, ad2, hA, sA, dA, N);
    // K7: final agg L2 (no relu,b2) -> out
    gat_aggregate_kernel<<<agg_grid, 256, 0, stream>>>(hA, sA, dA, rowptr, csr_src, b2, out, N);
}

// Round 12
// 293.133 us; speedup vs baseline: 1.0896x; 1.0896x over previous
//
#include <hip/hip_runtime.h>
#include <hip/hip_fp16.h>
#include <math.h>

#define WAVE 64
#define NEG_SLOPE 0.2f
#define LSTR 68   // padded LDS row stride (dwords)
#define CHUNK 8192

// ---------------------------------------------------------------------------
// CSR build: atomic-free two-level counting sort (bucket = 128 dst nodes).
// binned entries packed: (dst&127)<<16 | src  (N < 2^16).
// ---------------------------------------------------------------------------

// K1: blocks [0,nchunk) = per-chunk bucket partial counts; rest = gemm0 K=128.
__global__ __launch_bounds__(256) void count_gemm0_kernel(
    const int* __restrict__ dst, int* __restrict__ part, int e, int nb, int nchunk,
    const float* __restrict__ X, const float* __restrict__ W,
    const float* __restrict__ a_s, const float* __restrict__ a_d,
    __half* __restrict__ H, float* __restrict__ S, float* __restrict__ D, int n) {
    __shared__ float Xs[64 * LSTR];
    __shared__ float Ws[64 * LSTR];
    int t = threadIdx.x;

    if (blockIdx.x < nchunk) {
        int* cnt = (int*)Ws;
        for (int b = t; b < nb; b += 256) cnt[b] = 0;
        __syncthreads();
        int base = blockIdx.x * CHUNK;
#pragma unroll
        for (int k = 0; k < CHUNK / 256; ++k) {
            int i = base + k * 256 + t;
            if (i < e) atomicAdd(&cnt[dst[i] >> 7], 1);
        }
        __syncthreads();
        for (int b = t; b < nb; b += 256)
            part[(size_t)blockIdx.x * nb + b] = cnt[b];
        return;
    }

    constexpr int K = 128;
    int tx = t & 15;
    int ty = t >> 4;
    int base = (blockIdx.x - nchunk) * 64;
    float acc[4][4] = {};
    int q = t & 3;
    int srow = t >> 2;

    for (int k0 = 0; k0 < K; k0 += 64) {
        int grow = base + srow;
#pragma unroll
        for (int j = 0; j < 4; ++j) {
            int c = 16 * j + 4 * q;
            float4 v = make_float4(0.f, 0.f, 0.f, 0.f);
            if (grow < n) v = *(const float4*)(X + (size_t)grow * K + k0 + c);
            *(float4*)(Xs + srow * LSTR + c) = v;
            float4 w = *(const float4*)(W + (size_t)(k0 + srow) * 64 + c);
            *(float4*)(Ws + srow * LSTR + c) = w;
        }
        __syncthreads();
#pragma unroll 8
        for (int kk = 0; kk < 64; ++kk) {
            float4 wv = *(const float4*)(Ws + kk * LSTR + 4 * tx);
#pragma unroll
            for (int i = 0; i < 4; ++i) {
                float xv = Xs[(4 * ty + i) * LSTR + kk];
                acc[i][0] = fmaf(xv, wv.x, acc[i][0]);
                acc[i][1] = fmaf(xv, wv.y, acc[i][1]);
                acc[i][2] = fmaf(xv, wv.z, acc[i][2]);
                acc[i][3] = fmaf(xv, wv.w, acc[i][3]);
            }
        }
        __syncthreads();
    }

    const float4 av_s = *(const float4*)(a_s + 4 * tx);
    const float4 av_d = *(const float4*)(a_d + 4 * tx);
#pragma unroll
    for (int i = 0; i < 4; ++i) {
        int row = base + 4 * ty + i;
        bool ok = row < n;
        if (ok) {
            __half2 h01 = __floats2half2_rn(acc[i][0], acc[i][1]);
            __half2 h23 = __floats2half2_rn(acc[i][2], acc[i][3]);
            uint2 u;
            u.x = *(unsigned int*)&h01;
            u.y = *(unsigned int*)&h23;
            *(uint2*)(H + (size_t)row * 64 + 4 * tx) = u;
        }
        float ps = acc[i][0] * av_s.x + acc[i][1] * av_s.y +
                   acc[i][2] * av_s.z + acc[i][3] * av_s.w;
        float pd = acc[i][0] * av_d.x + acc[i][1] * av_d.y +
                   acc[i][2] * av_d.z + acc[i][3] * av_d.w;
        for (int o = 1; o < 16; o <<= 1) {
            ps += __shfl_xor(ps, o);
            pd += __shfl_xor(pd, o);
        }
        if (tx == 0 && ok) { S[row] = ps; D[row] = pd; }
    }
}

// K2: one block. part[c][b] -> intra-bucket chunk prefix; bucket -> boff.
__global__ __launch_bounds__(512) void bucket_scan_kernel(
    int* __restrict__ part, int* __restrict__ boff, int* __restrict__ rowptr,
    int nchunk, int nb, int e, int n) {
    __shared__ int sh[512];
    int t = threadIdx.x;
    int total = 0;
    if (t < nb) {
        int run = 0;
        for (int c = 0; c < nchunk; ++c) {
            size_t idx = (size_t)c * nb + t;
            int v = part[idx];
            part[idx] = run;
            run += v;
        }
        total = run;
    }
    sh[t] = total;
    __syncthreads();
    for (int o = 1; o < 512; o <<= 1) {
        int u = (t >= o) ? sh[t - o] : 0;
        __syncthreads();
        sh[t] += u;
        __syncthreads();
    }
    if (t < nb) boff[t] = sh[t] - total;
    if (t == 0) { boff[nb] = e; rowptr[n] = e + n; }
}

// K3: binned placement, no global atomics; packed 4B entries.
__global__ __launch_bounds__(256) void bucket_place_kernel(
    const int* __restrict__ src, const int* __restrict__ dst,
    const int* __restrict__ part, const int* __restrict__ boff,
    int* __restrict__ binned, int e, int nb) {
    extern __shared__ int lds[];
    int* cnt = lds;        // [nb]
    int* bas = lds + nb;   // [nb]
    int t = threadIdx.x;
    for (int b = t; b < nb; b += 256) cnt[b] = 0;
    __syncthreads();
    int base = blockIdx.x * CHUNK;
#pragma unroll
    for (int k = 0; k < CHUNK / 256; ++k) {
        int i = base + k * 256 + t;
        if (i < e) atomicAdd(&cnt[dst[i] >> 7], 1);
    }
    __syncthreads();
    for (int b = t; b < nb; b += 256) {
        bas[b] = boff[b] + part[(size_t)blockIdx.x * nb + b];
        cnt[b] = 0;
    }
    __syncthreads();
#pragma unroll
    for (int k = 0; k < CHUNK / 256; ++k) {
        int i = base + k * 256 + t;
        if (i < e) {
            int d = dst[i];
            int bk = d >> 7;
            int r = atomicAdd(&cnt[bk], 1);
            binned[bas[bk] + r] = ((d & 127) << 16) | src[i];
        }
    }
}

// K4: one block per bucket -> exact per-node CSR. Self loop at slot 0.
__global__ __launch_bounds__(256) void bucket_build_kernel(
    const int* __restrict__ binned, const int* __restrict__ boff,
    int* __restrict__ csr_src, int* __restrict__ rowptr, int n) {
    __shared__ int cnt[128], off[128], pcnt[128];
    int b = blockIdx.x;
    int t = threadIdx.x;
    int nodeBase = b << 7;
    int nc = min(128, n - nodeBase);
    int e0 = boff[b], e1 = boff[b + 1];
    int ne = e1 - e0;
    if (t < 128) { cnt[t] = 1; pcnt[t] = 1; }  // self-loop reserves slot 0
    __syncthreads();
    for (int i = t; i < ne; i += 256)
        atomicAdd(&cnt[binned[e0 + i] >> 16], 1);
    __syncthreads();
    if (t < 128) off[t] = cnt[t];
    __syncthreads();
    for (int o = 1; o < 128; o <<= 1) {
        int u = (t >= o && t < 128) ? off[t - o] : 0;
        __syncthreads();
        if (t < 128) off[t] += u;
        __syncthreads();
    }
    if (t < 128) off[t] -= cnt[t];  // exclusive
    __syncthreads();
    int csrBase = e0 + nodeBase;
    if (t < nc) {
        rowptr[nodeBase + t] = csrBase + off[t];
        csr_src[csrBase + off[t]] = nodeBase + t;  // self loop
    }
    for (int i = t; i < ne; i += 256) {
        int p = binned[e0 + i];
        int loc = p >> 16;
        int r = atomicAdd(&pcnt[loc], 1);
        csr_src[csrBase + off[loc] + r] = p & 0xFFFF;
    }
}

// ---------------------------------------------------------------------------
// Feature transform (layers 1,2): H(fp16) = X @ W (K=64); S,D logits.
// ---------------------------------------------------------------------------

__global__ __launch_bounds__(256) void gemm_feat_kernel(
    const float* __restrict__ X, const float* __restrict__ W,
    const float* __restrict__ a_s, const float* __restrict__ a_d,
    __half* __restrict__ H, float* __restrict__ S, float* __restrict__ D, int n) {
    constexpr int K = 64;
    __shared__ float Xs[64 * LSTR];
    __shared__ float Ws[64 * LSTR];
    int t = threadIdx.x;
    int tx = t & 15;
    int ty = t >> 4;
    int base = blockIdx.x * 64;
    float acc[4][4] = {};
    int q = t & 3;
    int srow = t >> 2;

    {
        int grow = base + srow;
#pragma unroll
        for (int j = 0; j < 4; ++j) {
            int c = 16 * j + 4 * q;
            float4 v = make_float4(0.f, 0.f, 0.f, 0.f);
            if (grow < n) v = *(const float4*)(X + (size_t)grow * K + c);
            *(float4*)(Xs + srow * LSTR + c) = v;
            float4 w = *(const float4*)(W + (size_t)srow * 64 + c);
            *(float4*)(Ws + srow * LSTR + c) = w;
        }
        __syncthreads();
#pragma unroll 8
        for (int kk = 0; kk < 64; ++kk) {
            float4 wv = *(const float4*)(Ws + kk * LSTR + 4 * tx);
#pragma unroll
            for (int i = 0; i < 4; ++i) {
                float xv = Xs[(4 * ty + i) * LSTR + kk];
                acc[i][0] = fmaf(xv, wv.x, acc[i][0]);
                acc[i][1] = fmaf(xv, wv.y, acc[i][1]);
                acc[i][2] = fmaf(xv, wv.z, acc[i][2]);
                acc[i][3] = fmaf(xv, wv.w, acc[i][3]);
            }
        }
    }

    const float4 av_s = *(const float4*)(a_s + 4 * tx);
    const float4 av_d = *(const float4*)(a_d + 4 * tx);
#pragma unroll
    for (int i = 0; i < 4; ++i) {
        int row = base + 4 * ty + i;
        bool ok = row < n;
        if (ok) {
            __half2 h01 = __floats2half2_rn(acc[i][0], acc[i][1]);
            __half2 h23 = __floats2half2_rn(acc[i][2], acc[i][3]);
            uint2 u;
            u.x = *(unsigned int*)&h01;
            u.y = *(unsigned int*)&h23;
            *(uint2*)(H + (size_t)row * 64 + 4 * tx) = u;
        }
        float ps = acc[i][0] * av_s.x + acc[i][1] * av_s.y +
                   acc[i][2] * av_s.z + acc[i][3] * av_s.w;
        float pd = acc[i][0] * av_d.x + acc[i][1] * av_d.y +
                   acc[i][2] * av_d.z + acc[i][3] * av_d.w;
        for (int o = 1; o < 16; o <<= 1) {
            ps += __shfl_xor(ps, o);
            pd += __shfl_xor(pd, o);
        }
        if (tx == 0 && ok) { S[row] = ps; D[row] = pd; }
    }
}

// ---------------------------------------------------------------------------
// GAT aggregation, one wave per dst node (standalone: node-waves retire
// independently -- no barrier-coupled load imbalance, unlike fused R9/R11).
// No max-shift; fp16 H gather (8B/lane); fp32 accumulate.
// ---------------------------------------------------------------------------

__global__ __launch_bounds__(256) void gat_aggregate_kernel(
    const __half* __restrict__ H, const float* __restrict__ S,
    const float* __restrict__ D, const int* __restrict__ rowptr,
    const int* __restrict__ csr_src, const float* __restrict__ bias,
    float* __restrict__ OUT, int n, int do_relu) {
    int wid  = (blockIdx.x * blockDim.x + threadIdx.x) >> 6;
    int lane = threadIdx.x & 63;
    if (wid >= n) return;
    int eg = lane >> 4;   // edge slot 0..3
    int cg = lane & 15;   // channel group: channels 4cg..4cg+3
    int start = rowptr[wid];
    int end   = rowptr[wid + 1];
    float d_i = D[wid];

    float z = 0.f;
    float4 acc = make_float4(0.f, 0.f, 0.f, 0.f);

    for (int cb = start; cb < end; cb += WAVE) {
        int j = cb + lane;
        bool v = j < end;
        int sc = v ? csr_src[j] : 0;
        float sv = S[sc];
        float e = sv + d_i;
        e = (e > 0.f) ? e : NEG_SLOPE * e;
        float w = v ? __expf(e) : 0.f;

        int nch = min(WAVE, end - cb);
        int rounds = (nch + 3) >> 2;
#pragma unroll 4
        for (int r = 0; r < rounds; ++r) {
            int idx = 4 * r + eg;
            float wr = __shfl(w, idx);
            int   sr = __shfl(sc, idx);
            float2 f0 = make_float2(0.f, 0.f), f1 = f0;
            if (idx < nch) {
                uint2 u = *(const uint2*)(H + (size_t)sr * 64 + 4 * cg);
                f0 = __half22float2(*(__half2*)&u.x);
                f1 = __half22float2(*(__half2*)&u.y);
            }
            z += wr;
            acc.x = fmaf(wr, f0.x, acc.x);
            acc.y = fmaf(wr, f0.y, acc.y);
            acc.z = fmaf(wr, f1.x, acc.z);
            acc.w = fmaf(wr, f1.y, acc.w);
        }
    }

    for (int o = 16; o < 64; o <<= 1) {
        acc.x += __shfl_xor(acc.x, o);
        acc.y += __shfl_xor(acc.y, o);
        acc.z += __shfl_xor(acc.z, o);
        acc.w += __shfl_xor(acc.w, o);
        z     += __shfl_xor(z, o);
    }

    if (eg == 0) {
        float inv = 1.f / (z + 1e-16f);
        const float4 bv = *(const float4*)(bias + 4 * cg);
        float4 o4;
        o4.x = acc.x * inv + bv.x;
        o4.y = acc.y * inv + bv.y;
        o4.z = acc.z * inv + bv.z;
        o4.w = acc.w * inv + bv.w;
        if (do_relu) {
            o4.x = fmaxf(o4.x, 0.f); o4.y = fmaxf(o4.y, 0.f);
            o4.z = fmaxf(o4.z, 0.f); o4.w = fmaxf(o4.w, 0.f);
        }
        *(float4*)(OUT + (size_t)wid * 64 + 4 * cg) = o4;
    }
}

// ---------------------------------------------------------------------------

static inline size_t align256(size_t x) { return (x + 255) & ~(size_t)255; }

extern "C" void kernel_launch(void* const* d_in, const int* in_sizes, int n_in,
                              void* d_out, int out_size, void* d_ws, size_t ws_size,
                              hipStream_t stream) {
    const float* x    = (const float*)d_in[0];
    const int*   esrc = (const int*)d_in[1];
    const int*   edst = (const int*)d_in[2];
    const int E = in_sizes[1];
    const int N = in_sizes[0] / 128;

    const float* W0 = (const float*)d_in[3];
    const float* as0 = (const float*)d_in[4];
    const float* ad0 = (const float*)d_in[5];
    const float* b0 = (const float*)d_in[6];
    const float* W1 = (const float*)d_in[7];
    const float* as1 = (const float*)d_in[8];
    const float* ad1 = (const float*)d_in[9];
    const float* b1 = (const float*)d_in[10];
    const float* W2 = (const float*)d_in[11];
    const float* as2 = (const float*)d_in[12];
    const float* ad2 = (const float*)d_in[13];
    const float* b2 = (const float*)d_in[14];

    const int NB = (N + 127) >> 7;               // buckets (<=512 for scan)
    const int nchunk = (E + CHUNK - 1) / CHUNK;  // 98 here

    // workspace layout
    char* p = (char*)d_ws;
    int* part    = (int*)p; p += align256((size_t)nchunk * NB * 4);
    int* boff    = (int*)p; p += align256((size_t)(NB + 1) * 4);
    int* rowptr  = (int*)p; p += align256((size_t)(N + 1) * 4);
    int* csr_src = (int*)p; p += align256((size_t)(E + N) * 4);
    int* binned  = (int*)p; p += align256((size_t)E * 4);
    __half* h16 = (__half*)p; p += align256((size_t)N * 64 * 2);
    float* sA = (float*)p; p += align256((size_t)N * 4);
    float* dA = (float*)p; p += align256((size_t)N * 4);
    float* XA = (float*)p; p += align256((size_t)N * 64 * 4);
    float* XB = (float*)p; p += align256((size_t)N * 64 * 4);
    float* out = (float*)d_out;

    int tile_grid = (N + 63) / 64;
    int agg_grid  = (N + 3) / 4;

    // K1: bucket partial counts || gemm0 (x @ W0 -> h16, sA, dA)
    count_gemm0_kernel<<<nchunk + tile_grid, 256, 0, stream>>>(
        edst, part, E, NB, nchunk, x, W0, as0, ad0, h16, sA, dA, N);
    // K2..K4: CSR (atomic-free placement, packed 4B entries)
    bucket_scan_kernel<<<1, 512, 0, stream>>>(part, boff, rowptr, nchunk, NB, E, N);
    bucket_place_kernel<<<nchunk, 256, 2 * NB * 4, stream>>>(esrc, edst, part, boff, binned, E, NB);
    bucket_build_kernel<<<NB, 256, 0, stream>>>(binned, boff, csr_src, rowptr, N);

    // layer 0 agg (relu,b0) -> XA
    gat_aggregate_kernel<<<agg_grid, 256, 0, stream>>>(h16, sA, dA, rowptr, csr_src, b0, XA, N, 1);
    // layer 1: gemm -> h16; agg (relu,b1) -> XB
    gemm_feat_kernel<<<tile_grid, 256, 0, stream>>>(XA, W1, as1, ad1, h16, sA, dA, N);
    gat_aggregate_kernel<<<agg_grid, 256, 0, stream>>>(h16, sA, dA, rowptr, csr_src, b1, XB, N, 1);
    // layer 2: gemm -> h16; agg (no relu,b2) -> out
    gemm_feat_kernel<<<tile_grid, 256, 0, stream>>>(XB, W2, as2, ad2, h16, sA, dA, N);
    gat_aggregate_kernel<<<agg_grid, 256, 0, stream>>>(h16, sA, dA, rowptr, csr_src, b2, out, N, 0);
}

// Round 13
// 271.208 us; speedup vs baseline: 1.1777x; 1.0808x over previous
//
#include <hip/hip_runtime.h>
#include <hip/hip_fp16.h>
#include <math.h>

#define WAVE 64
#define NEG_SLOPE 0.2f
#define LSTR 68  // padded LDS row stride (dwords)

// ---------------------------------------------------------------------------
// CSR build via two-level counting sort (bucket = 128 consecutive dst nodes).
// R10 structure (global bucket atomics — measured cheaper than the R12
// "atomic-free" rework, which regressed 21 us). binned entries packed to 4B:
// (dst&127)<<16 | src  (N < 2^16).
// ---------------------------------------------------------------------------

__global__ __launch_bounds__(256) void bucket_count_kernel(
    const int* __restrict__ dst, int* __restrict__ gcnt, int e, int nb) {
    extern __shared__ int cnt[];
    for (int b = threadIdx.x; b < nb; b += 256) cnt[b] = 0;
    __syncthreads();
    int base = blockIdx.x * 4096;
#pragma unroll
    for (int k = 0; k < 16; ++k) {
        int i = base + k * 256 + threadIdx.x;
        if (i < e) atomicAdd(&cnt[dst[i] >> 7], 1);
    }
    __syncthreads();
    for (int b = threadIdx.x; b < nb; b += 256) {
        int c = cnt[b];
        if (c) atomicAdd(&gcnt[b], c);
    }
}

__global__ __launch_bounds__(512) void bucket_scan_kernel(
    const int* __restrict__ gcnt, int* __restrict__ boff, int* __restrict__ gfill,
    int* __restrict__ rowptr, int nb, int e, int n) {
    __shared__ int sh[512];
    int t = threadIdx.x;
    int v = (t < nb) ? gcnt[t] : 0;
    sh[t] = v;
    __syncthreads();
    for (int o = 1; o < 512; o <<= 1) {
        int u = (t >= o) ? sh[t - o] : 0;
        __syncthreads();
        sh[t] += u;
        __syncthreads();
    }
    if (t < nb) { int ex = sh[t] - v; boff[t] = ex; gfill[t] = ex; }
    if (t == 0) { boff[nb] = e; rowptr[n] = e + n; }
}

__global__ __launch_bounds__(256) void bucket_place_kernel(
    const int* __restrict__ src, const int* __restrict__ dst,
    int* __restrict__ gfill, int* __restrict__ binned, int e, int nb) {
    extern __shared__ int lds[];
    int* cnt = lds;        // [nb]
    int* bas = lds + nb;   // [nb]
    for (int b = threadIdx.x; b < nb; b += 256) cnt[b] = 0;
    __syncthreads();
    int base = blockIdx.x * 4096;
#pragma unroll
    for (int k = 0; k < 16; ++k) {
        int i = base + k * 256 + threadIdx.x;
        if (i < e) atomicAdd(&cnt[dst[i] >> 7], 1);
    }
    __syncthreads();
    for (int b = threadIdx.x; b < nb; b += 256) {
        int c = cnt[b];
        bas[b] = c ? atomicAdd(&gfill[b], c) : 0;
        cnt[b] = 0;
    }
    __syncthreads();
#pragma unroll
    for (int k = 0; k < 16; ++k) {
        int i = base + k * 256 + threadIdx.x;
        if (i < e) {
            int d = dst[i];
            int bk = d >> 7;
            int r = atomicAdd(&cnt[bk], 1);
            binned[bas[bk] + r] = ((d & 127) << 16) | src[i];
        }
    }
}

__global__ __launch_bounds__(256) void bucket_build_kernel(
    const int* __restrict__ binned, const int* __restrict__ boff,
    int* __restrict__ csr_src, int* __restrict__ rowptr, int n) {
    __shared__ int cnt[128], off[128], pcnt[128];
    int b = blockIdx.x;
    int t = threadIdx.x;
    int nodeBase = b << 7;
    int nc = min(128, n - nodeBase);
    int e0 = boff[b], e1 = boff[b + 1];
    int ne = e1 - e0;
    if (t < 128) { cnt[t] = 1; pcnt[t] = 1; }  // self-loop reserves slot 0
    __syncthreads();
    for (int i = t; i < ne; i += 256)
        atomicAdd(&cnt[binned[e0 + i] >> 16], 1);
    __syncthreads();
    if (t < 128) off[t] = cnt[t];
    __syncthreads();
    for (int o = 1; o < 128; o <<= 1) {
        int u = (t >= o && t < 128) ? off[t - o] : 0;
        __syncthreads();
        if (t < 128) off[t] += u;
        __syncthreads();
    }
    if (t < 128) off[t] -= cnt[t];  // exclusive
    __syncthreads();
    int csrBase = e0 + nodeBase;
    if (t < nc) {
        rowptr[nodeBase + t] = csrBase + off[t];
        csr_src[csrBase + off[t]] = nodeBase + t;  // self loop
    }
    for (int i = t; i < ne; i += 256) {
        int p = binned[e0 + i];
        int loc = p >> 16;
        int r = atomicAdd(&pcnt[loc], 1);
        csr_src[csrBase + off[loc] + r] = p & 0xFFFF;
    }
}

// ---------------------------------------------------------------------------
// Feature transform: H(fp16) = X @ W ;  S = H . a_src ;  D = H . a_dst
// Register-tiled: 256 threads = 16x16, 4x4 micro-tile per thread.
// ---------------------------------------------------------------------------

template <int K>
__global__ __launch_bounds__(256) void gemm_feat_kernel(
    const float* __restrict__ X, const float* __restrict__ W,
    const float* __restrict__ a_s, const float* __restrict__ a_d,
    __half* __restrict__ H, float* __restrict__ S, float* __restrict__ D, int n) {
    __shared__ float Xs[64 * LSTR];
    __shared__ float Ws[64 * LSTR];
    int t = threadIdx.x;
    int tx = t & 15;
    int ty = t >> 4;
    int base = blockIdx.x * 64;
    float acc[4][4] = {};

    int q = t & 3;
    int srow = t >> 2;

    for (int k0 = 0; k0 < K; k0 += 64) {
        int grow = base + srow;
#pragma unroll
        for (int j = 0; j < 4; ++j) {
            int c = 16 * j + 4 * q;
            float4 v = make_float4(0.f, 0.f, 0.f, 0.f);
            if (grow < n) v = *(const float4*)(X + (size_t)grow * K + k0 + c);
            *(float4*)(Xs + srow * LSTR + c) = v;
            float4 w = *(const float4*)(W + (size_t)(k0 + srow) * 64 + c);
            *(float4*)(Ws + srow * LSTR + c) = w;
        }
        __syncthreads();
#pragma unroll 8
        for (int kk = 0; kk < 64; ++kk) {
            float4 wv = *(const float4*)(Ws + kk * LSTR + 4 * tx);
#pragma unroll
            for (int i = 0; i < 4; ++i) {
                float xv = Xs[(4 * ty + i) * LSTR + kk];
                acc[i][0] = fmaf(xv, wv.x, acc[i][0]);
                acc[i][1] = fmaf(xv, wv.y, acc[i][1]);
                acc[i][2] = fmaf(xv, wv.z, acc[i][2]);
                acc[i][3] = fmaf(xv, wv.w, acc[i][3]);
            }
        }
        __syncthreads();
    }

    const float4 av_s = *(const float4*)(a_s + 4 * tx);
    const float4 av_d = *(const float4*)(a_d + 4 * tx);
#pragma unroll
    for (int i = 0; i < 4; ++i) {
        int row = base + 4 * ty + i;
        bool ok = row < n;
        if (ok) {
            __half2 h01 = __floats2half2_rn(acc[i][0], acc[i][1]);
            __half2 h23 = __floats2half2_rn(acc[i][2], acc[i][3]);
            uint2 u;
            u.x = *(unsigned int*)&h01;
            u.y = *(unsigned int*)&h23;
            *(uint2*)(H + (size_t)row * 64 + 4 * tx) = u;  // 8B aligned
        }
        float ps = acc[i][0] * av_s.x + acc[i][1] * av_s.y +
                   acc[i][2] * av_s.z + acc[i][3] * av_s.w;
        float pd = acc[i][0] * av_d.x + acc[i][1] * av_d.y +
                   acc[i][2] * av_d.z + acc[i][3] * av_d.w;
        for (int o = 1; o < 16; o <<= 1) {
            ps += __shfl_xor(ps, o);
            pd += __shfl_xor(pd, o);
        }
        if (tx == 0 && ok) { S[row] = ps; D[row] = pd; }
    }
}

// ---------------------------------------------------------------------------
// GAT aggregation, one wave per dst node. No max-shift (logits O(+-10),
// fp32 exp cannot overflow). H gathered as fp16 (8B/lane), accumulate fp32.
// Phase 1 (lane=edge): coalesced csr load + S gather + exp.
// Phase 2 (4 edge-slots x 16 channel-groups): shfl-broadcast (w,src);
// masked 8B loads, unroll 4 -> 16 independent lines in flight per wave.
// ---------------------------------------------------------------------------

__global__ __launch_bounds__(256) void gat_aggregate_kernel(
    const __half* __restrict__ H, const float* __restrict__ S,
    const float* __restrict__ D, const int* __restrict__ rowptr,
    const int* __restrict__ csr_src, const float* __restrict__ bias,
    float* __restrict__ OUT, int n, int do_relu) {
    int wid  = (blockIdx.x * blockDim.x + threadIdx.x) >> 6;
    int lane = threadIdx.x & 63;
    if (wid >= n) return;
    int eg = lane >> 4;   // edge slot 0..3
    int cg = lane & 15;   // channel group: channels 4cg..4cg+3
    int start = rowptr[wid];
    int end   = rowptr[wid + 1];
    float d_i = D[wid];

    float z = 0.f;
    float4 acc = make_float4(0.f, 0.f, 0.f, 0.f);

    for (int cb = start; cb < end; cb += WAVE) {
        // Phase 1: lane = edge
        int j = cb + lane;
        bool v = j < end;
        int sc = v ? csr_src[j] : 0;
        float sv = S[sc];
        float e = sv + d_i;
        e = (e > 0.f) ? e : NEG_SLOPE * e;
        float w = v ? __expf(e) : 0.f;

        // Phase 2
        int nch = min(WAVE, end - cb);
        int rounds = (nch + 3) >> 2;
#pragma unroll 4
        for (int r = 0; r < rounds; ++r) {
            int idx = 4 * r + eg;
            float wr = __shfl(w, idx);
            int   sr = __shfl(sc, idx);
            float2 f0 = make_float2(0.f, 0.f), f1 = f0;
            if (idx < nch) {
                uint2 u = *(const uint2*)(H + (size_t)sr * 64 + 4 * cg);
                f0 = __half22float2(*(__half2*)&u.x);
                f1 = __half22float2(*(__half2*)&u.y);
            }
            z += wr;
            acc.x = fmaf(wr, f0.x, acc.x);
            acc.y = fmaf(wr, f0.y, acc.y);
            acc.z = fmaf(wr, f1.x, acc.z);
            acc.w = fmaf(wr, f1.y, acc.w);
        }
    }

    for (int o = 16; o < 64; o <<= 1) {
        acc.x += __shfl_xor(acc.x, o);
        acc.y += __shfl_xor(acc.y, o);
        acc.z += __shfl_xor(acc.z, o);
        acc.w += __shfl_xor(acc.w, o);
        z     += __shfl_xor(z, o);
    }

    if (eg == 0) {
        float inv = 1.f / (z + 1e-16f);
        const float4 bv = *(const float4*)(bias + 4 * cg);
        float4 o4;
        o4.x = acc.x * inv + bv.x;
        o4.y = acc.y * inv + bv.y;
        o4.z = acc.z * inv + bv.z;
        o4.w = acc.w * inv + bv.w;
        if (do_relu) {
            o4.x = fmaxf(o4.x, 0.f); o4.y = fmaxf(o4.y, 0.f);
            o4.z = fmaxf(o4.z, 0.f); o4.w = fmaxf(o4.w, 0.f);
        }
        *(float4*)(OUT + (size_t)wid * 64 + 4 * cg) = o4;
    }
}

// ---------------------------------------------------------------------------

static inline size_t align256(size_t x) { return (x + 255) & ~(size_t)255; }

extern "C" void kernel_launch(void* const* d_in, const int* in_sizes, int n_in,
                              void* d_out, int out_size, void* d_ws, size_t ws_size,
                              hipStream_t stream) {
    const float* x    = (const float*)d_in[0];
    const int*   esrc = (const int*)d_in[1];
    const int*   edst = (const int*)d_in[2];
    const int E = in_sizes[1];
    const int N = in_sizes[0] / 128;

    const float* W0 = (const float*)d_in[3];
    const float* as0 = (const float*)d_in[4];
    const float* ad0 = (const float*)d_in[5];
    const float* b0 = (const float*)d_in[6];
    const float* W1 = (const float*)d_in[7];
    const float* as1 = (const float*)d_in[8];
    const float* ad1 = (const float*)d_in[9];
    const float* b1 = (const float*)d_in[10];
    const float* W2 = (const float*)d_in[11];
    const float* as2 = (const float*)d_in[12];
    const float* ad2 = (const float*)d_in[13];
    const float* b2 = (const float*)d_in[14];

    const int NB = (N + 127) >> 7;  // buckets of 128 nodes (<=512 for scan)

    // workspace layout
    char* p = (char*)d_ws;
    int* gcnt    = (int*)p; p += align256((size_t)(NB + 1) * 4);
    int* boff    = (int*)p; p += align256((size_t)(NB + 1) * 4);
    int* gfill   = (int*)p; p += align256((size_t)(NB + 1) * 4);
    int* rowptr  = (int*)p; p += align256((size_t)(N + 1) * 4);
    int* csr_src = (int*)p; p += align256((size_t)(E + N) * 4);
    int* binned  = (int*)p; p += align256((size_t)E * 4);
    __half* h16 = (__half*)p; p += align256((size_t)N * 64 * 2);
    float* sA = (float*)p; p += align256((size_t)N * 4);
    float* dA = (float*)p; p += align256((size_t)N * 4);
    float* XA = (float*)p; p += align256((size_t)N * 64 * 4);
    float* XB = (float*)p; p += align256((size_t)N * 64 * 4);
    float* out = (float*)d_out;

    // ---- CSR build (two-level counting sort) ----
    int nchunk = (E + 4095) / 4096;
    hipMemsetAsync(gcnt, 0, (size_t)(NB + 1) * 4, stream);
    bucket_count_kernel<<<nchunk, 256, NB * 4, stream>>>(edst, gcnt, E, NB);
    bucket_scan_kernel<<<1, 512, 0, stream>>>(gcnt, boff, gfill, rowptr, NB, E, N);
    bucket_place_kernel<<<nchunk, 256, 2 * NB * 4, stream>>>(esrc, edst, gfill, binned, E, NB);
    bucket_build_kernel<<<NB, 256, 0, stream>>>(binned, boff, csr_src, rowptr, N);

    int tile_grid = (N + 63) / 64;
    int agg_grid  = (N + 3) / 4;

    // ---- layer 0: 128 -> 64, relu ----
    gemm_feat_kernel<128><<<tile_grid, 256, 0, stream>>>(x, W0, as0, ad0, h16, sA, dA, N);
    gat_aggregate_kernel<<<agg_grid, 256, 0, stream>>>(h16, sA, dA, rowptr, csr_src, b0, XA, N, 1);

    // ---- layer 1: 64 -> 64, relu ----
    gemm_feat_kernel<64><<<tile_grid, 256, 0, stream>>>(XA, W1, as1, ad1, h16, sA, dA, N);
    gat_aggregate_kernel<<<agg_grid, 256, 0, stream>>>(h16, sA, dA, rowptr, csr_src, b1, XB, N, 1);

    // ---- layer 2: 64 -> 64, no relu ----
    gemm_feat_kernel<64><<<tile_grid, 256, 0, stream>>>(XB, W2, as2, ad2, h16, sA, dA, N);
    gat_aggregate_kernel<<<agg_grid, 256, 0, stream>>>(h16, sA, dA, rowptr, csr_src, b2, out, N, 0);
}

// Round 14
// 257.796 us; speedup vs baseline: 1.2389x; 1.0520x over previous
//
#include <hip/hip_runtime.h>
#include <hip/hip_fp16.h>
#include <math.h>

#define WAVE 64
#define NEG_SLOPE 0.2f
#define LSTR 68  // padded LDS row stride for fp32 tiles (dwords)

typedef _Float16 half8 __attribute__((ext_vector_type(8)));
typedef float f32x4 __attribute__((ext_vector_type(4)));

// ---------------------------------------------------------------------------
// CSR build via two-level counting sort (bucket = 128 consecutive dst nodes).
// R10/R13 structure (global bucket atomics; R12 "atomic-free" rework measured
// 21 us slower). binned entries packed 4B: (dst&127)<<16 | src  (N < 2^16).
// ---------------------------------------------------------------------------

__global__ __launch_bounds__(256) void bucket_count_kernel(
    const int* __restrict__ dst, int* __restrict__ gcnt, int e, int nb) {
    extern __shared__ int cnt[];
    for (int b = threadIdx.x; b < nb; b += 256) cnt[b] = 0;
    __syncthreads();
    int base = blockIdx.x * 4096;
#pragma unroll
    for (int k = 0; k < 16; ++k) {
        int i = base + k * 256 + threadIdx.x;
        if (i < e) atomicAdd(&cnt[dst[i] >> 7], 1);
    }
    __syncthreads();
    for (int b = threadIdx.x; b < nb; b += 256) {
        int c = cnt[b];
        if (c) atomicAdd(&gcnt[b], c);
    }
}

__global__ __launch_bounds__(512) void bucket_scan_kernel(
    const int* __restrict__ gcnt, int* __restrict__ boff, int* __restrict__ gfill,
    int* __restrict__ rowptr, int nb, int e, int n) {
    __shared__ int sh[512];
    int t = threadIdx.x;
    int v = (t < nb) ? gcnt[t] : 0;
    sh[t] = v;
    __syncthreads();
    for (int o = 1; o < 512; o <<= 1) {
        int u = (t >= o) ? sh[t - o] : 0;
        __syncthreads();
        sh[t] += u;
        __syncthreads();
    }
    if (t < nb) { int ex = sh[t] - v; boff[t] = ex; gfill[t] = ex; }
    if (t == 0) { boff[nb] = e; rowptr[n] = e + n; }
}

__global__ __launch_bounds__(256) void bucket_place_kernel(
    const int* __restrict__ src, const int* __restrict__ dst,
    int* __restrict__ gfill, int* __restrict__ binned, int e, int nb) {
    extern __shared__ int lds[];
    int* cnt = lds;        // [nb]
    int* bas = lds + nb;   // [nb]
    for (int b = threadIdx.x; b < nb; b += 256) cnt[b] = 0;
    __syncthreads();
    int base = blockIdx.x * 4096;
#pragma unroll
    for (int k = 0; k < 16; ++k) {
        int i = base + k * 256 + threadIdx.x;
        if (i < e) atomicAdd(&cnt[dst[i] >> 7], 1);
    }
    __syncthreads();
    for (int b = threadIdx.x; b < nb; b += 256) {
        int c = cnt[b];
        bas[b] = c ? atomicAdd(&gfill[b], c) : 0;
        cnt[b] = 0;
    }
    __syncthreads();
#pragma unroll
    for (int k = 0; k < 16; ++k) {
        int i = base + k * 256 + threadIdx.x;
        if (i < e) {
            int d = dst[i];
            int bk = d >> 7;
            int r = atomicAdd(&cnt[bk], 1);
            binned[bas[bk] + r] = ((d & 127) << 16) | src[i];
        }
    }
}

__global__ __launch_bounds__(256) void bucket_build_kernel(
    const int* __restrict__ binned, const int* __restrict__ boff,
    int* __restrict__ csr_src, int* __restrict__ rowptr, int n) {
    __shared__ int cnt[128], off[128], pcnt[128];
    int b = blockIdx.x;
    int t = threadIdx.x;
    int nodeBase = b << 7;
    int nc = min(128, n - nodeBase);
    int e0 = boff[b], e1 = boff[b + 1];
    int ne = e1 - e0;
    if (t < 128) { cnt[t] = 1; pcnt[t] = 1; }  // self-loop reserves slot 0
    __syncthreads();
    for (int i = t; i < ne; i += 256)
        atomicAdd(&cnt[binned[e0 + i] >> 16], 1);
    __syncthreads();
    if (t < 128) off[t] = cnt[t];
    __syncthreads();
    for (int o = 1; o < 128; o <<= 1) {
        int u = (t >= o && t < 128) ? off[t - o] : 0;
        __syncthreads();
        if (t < 128) off[t] += u;
        __syncthreads();
    }
    if (t < 128) off[t] -= cnt[t];  // exclusive
    __syncthreads();
    int csrBase = e0 + nodeBase;
    if (t < nc) {
        rowptr[nodeBase + t] = csrBase + off[t];
        csr_src[csrBase + off[t]] = nodeBase + t;  // self loop
    }
    for (int i = t; i < ne; i += 256) {
        int p = binned[e0 + i];
        int loc = p >> 16;
        int r = atomicAdd(&pcnt[loc], 1);
        csr_src[csrBase + off[loc] + r] = p & 0xFFFF;
    }
}

// ---------------------------------------------------------------------------
// MFMA feature transform: H(fp16) = X @ W ; S = H.a_src ; D = H.a_dst.
// mfma_f32_16x16x32_f16; 4 waves/block, wave = 16-row strip of the 64x64 tile.
// Verified layouts (guide S3/m89/m120): A[m=lane&15][k=(lane>>4)*8+j];
// B loaded from W^T LDS tile with the mirrored mapping; C col=lane&15,
// row=(lane>>4)*4+reg. X (fp32) and W (fp32) converted to fp16 at staging.
// Strides K+8 halves: 16B-aligned b128 frags, <=2-way bank alias (free).
// ---------------------------------------------------------------------------

template <int K>
__global__ __launch_bounds__(256) void mfma_gemm_feat_kernel(
    const float* __restrict__ X, const float* __restrict__ W,
    const float* __restrict__ a_s, const float* __restrict__ a_d,
    __half* __restrict__ H, float* __restrict__ S, float* __restrict__ D, int n) {
    constexpr int AK = K + 8;  // LDS row stride in halves
    __shared__ _Float16 Xs[64 * AK];
    __shared__ _Float16 Bt[64 * AK];
    int t = threadIdx.x;
    int base = blockIdx.x * 64;

    // stage X -> fp16 (row = t>>2, quarter q = t&3 covers K/4 cols)
    {
        int row = t >> 2, q = t & 3;
        int grow = base + row;
        constexpr int CW = K / 4;
#pragma unroll
        for (int c0 = 0; c0 < CW; c0 += 8) {
            float4 v0 = make_float4(0.f, 0.f, 0.f, 0.f), v1 = v0;
            if (grow < n) {
                v0 = *(const float4*)(X + (size_t)grow * K + q * CW + c0);
                v1 = *(const float4*)(X + (size_t)grow * K + q * CW + c0 + 4);
            }
            _Float16 h[8] = {(_Float16)v0.x, (_Float16)v0.y, (_Float16)v0.z, (_Float16)v0.w,
                             (_Float16)v1.x, (_Float16)v1.y, (_Float16)v1.z, (_Float16)v1.w};
            *(uint4*)(Xs + row * AK + q * CW + c0) = *(uint4*)h;
        }
    }
    // stage W^T -> fp16: Bt[n][k]; thread (n = t&63, g = t>>6) covers K/4 k's
    {
        int nn = t & 63, g = t >> 6;
        constexpr int KW = K / 4;
        _Float16 hbuf[KW];
#pragma unroll
        for (int j = 0; j < KW; ++j)
            hbuf[j] = (_Float16)W[(size_t)(g * KW + j) * 64 + nn];
#pragma unroll
        for (int j = 0; j < KW; j += 8)
            *(uint4*)(Bt + nn * AK + g * KW + j) = *(uint4*)(hbuf + j);
    }
    __syncthreads();

    int lane = t & 63;
    int wv = t >> 6;
    int m0 = wv * 16;          // wave's row strip
    int l15 = lane & 15, quad = lane >> 4;

    f32x4 acc[4] = {{0.f, 0.f, 0.f, 0.f}, {0.f, 0.f, 0.f, 0.f},
                    {0.f, 0.f, 0.f, 0.f}, {0.f, 0.f, 0.f, 0.f}};
#pragma unroll
    for (int ks = 0; ks < K; ks += 32) {
        half8 a = *(half8*)(Xs + (m0 + l15) * AK + ks + quad * 8);
#pragma unroll
        for (int cg = 0; cg < 4; ++cg) {
            half8 b = *(half8*)(Bt + (cg * 16 + l15) * AK + ks + quad * 8);
            acc[cg] = __builtin_amdgcn_mfma_f32_16x16x32_f16(a, b, acc[cg], 0, 0, 0);
        }
    }

    // epilogue: C[row = m0+quad*4+r][col = cg*16+l15] = acc[cg][r]
    float as_c[4], ad_c[4];
#pragma unroll
    for (int cg = 0; cg < 4; ++cg) {
        as_c[cg] = a_s[cg * 16 + l15];
        ad_c[cg] = a_d[cg * 16 + l15];
    }
#pragma unroll
    for (int r = 0; r < 4; ++r) {
        int grow = base + m0 + quad * 4 + r;
        bool ok = grow < n;
        float ps = 0.f, pd = 0.f;
#pragma unroll
        for (int cg = 0; cg < 4; ++cg) {
            float v = acc[cg][r];
            if (ok) H[(size_t)grow * 64 + cg * 16 + l15] = __float2half(v);
            ps += v * as_c[cg];
            pd += v * ad_c[cg];
        }
        for (int o = 1; o < 16; o <<= 1) {
            ps += __shfl_xor(ps, o);
            pd += __shfl_xor(pd, o);
        }
        if (l15 == 0 && ok) { S[grow] = ps; D[grow] = pd; }
    }
}

// ---------------------------------------------------------------------------
// GAT aggregation, one wave per dst node. No max-shift (logits O(+-10),
// fp32 exp cannot overflow). H gathered as fp16 (8B/lane), accumulate fp32.
// Phase 1 (lane=edge): coalesced csr load + S gather + exp.
// Phase 2 (4 edge-slots x 16 channel-groups): shfl-broadcast (w,src);
// masked 8B loads, unroll 4 -> 16 independent lines in flight per wave.
// ---------------------------------------------------------------------------

__global__ __launch_bounds__(256) void gat_aggregate_kernel(
    const __half* __restrict__ H, const float* __restrict__ S,
    const float* __restrict__ D, const int* __restrict__ rowptr,
    const int* __restrict__ csr_src, const float* __restrict__ bias,
    float* __restrict__ OUT, int n, int do_relu) {
    int wid  = (blockIdx.x * blockDim.x + threadIdx.x) >> 6;
    int lane = threadIdx.x & 63;
    if (wid >= n) return;
    int eg = lane >> 4;   // edge slot 0..3
    int cg = lane & 15;   // channel group: channels 4cg..4cg+3
    int start = rowptr[wid];
    int end   = rowptr[wid + 1];
    float d_i = D[wid];

    float z = 0.f;
    float4 acc = make_float4(0.f, 0.f, 0.f, 0.f);

    for (int cb = start; cb < end; cb += WAVE) {
        int j = cb + lane;
        bool v = j < end;
        int sc = v ? csr_src[j] : 0;
        float sv = S[sc];
        float e = sv + d_i;
        e = (e > 0.f) ? e : NEG_SLOPE * e;
        float w = v ? __expf(e) : 0.f;

        int nch = min(WAVE, end - cb);
        int rounds = (nch + 3) >> 2;
#pragma unroll 4
        for (int r = 0; r < rounds; ++r) {
            int idx = 4 * r + eg;
            float wr = __shfl(w, idx);
            int   sr = __shfl(sc, idx);
            float2 f0 = make_float2(0.f, 0.f), f1 = f0;
            if (idx < nch) {
                uint2 u = *(const uint2*)(H + (size_t)sr * 64 + 4 * cg);
                f0 = __half22float2(*(__half2*)&u.x);
                f1 = __half22float2(*(__half2*)&u.y);
            }
            z += wr;
            acc.x = fmaf(wr, f0.x, acc.x);
            acc.y = fmaf(wr, f0.y, acc.y);
            acc.z = fmaf(wr, f1.x, acc.z);
            acc.w = fmaf(wr, f1.y, acc.w);
        }
    }

    for (int o = 16; o < 64; o <<= 1) {
        acc.x += __shfl_xor(acc.x, o);
        acc.y += __shfl_xor(acc.y, o);
        acc.z += __shfl_xor(acc.z, o);
        acc.w += __shfl_xor(acc.w, o);
        z     += __shfl_xor(z, o);
    }

    if (eg == 0) {
        float inv = 1.f / (z + 1e-16f);
        const float4 bv = *(const float4*)(bias + 4 * cg);
        float4 o4;
        o4.x = acc.x * inv + bv.x;
        o4.y = acc.y * inv + bv.y;
        o4.z = acc.z * inv + bv.z;
        o4.w = acc.w * inv + bv.w;
        if (do_relu) {
            o4.x = fmaxf(o4.x, 0.f); o4.y = fmaxf(o4.y, 0.f);
            o4.z = fmaxf(o4.z, 0.f); o4.w = fmaxf(o4.w, 0.f);
        }
        *(float4*)(OUT + (size_t)wid * 64 + 4 * cg) = o4;
    }
}

// ---------------------------------------------------------------------------

static inline size_t align256(size_t x) { return (x + 255) & ~(size_t)255; }

extern "C" void kernel_launch(void* const* d_in, const int* in_sizes, int n_in,
                              void* d_out, int out_size, void* d_ws, size_t ws_size,
                              hipStream_t stream) {
    const float* x    = (const float*)d_in[0];
    const int*   esrc = (const int*)d_in[1];
    const int*   edst = (const int*)d_in[2];
    const int E = in_sizes[1];
    const int N = in_sizes[0] / 128;

    const float* W0 = (const float*)d_in[3];
    const float* as0 = (const float*)d_in[4];
    const float* ad0 = (const float*)d_in[5];
    const float* b0 = (const float*)d_in[6];
    const float* W1 = (const float*)d_in[7];
    const float* as1 = (const float*)d_in[8];
    const float* ad1 = (const float*)d_in[9];
    const float* b1 = (const float*)d_in[10];
    const float* W2 = (const float*)d_in[11];
    const float* as2 = (const float*)d_in[12];
    const float* ad2 = (const float*)d_in[13];
    const float* b2 = (const float*)d_in[14];

    const int NB = (N + 127) >> 7;  // buckets of 128 nodes (<=512 for scan)

    // workspace layout
    char* p = (char*)d_ws;
    int* gcnt    = (int*)p; p += align256((size_t)(NB + 1) * 4);
    int* boff    = (int*)p; p += align256((size_t)(NB + 1) * 4);
    int* gfill   = (int*)p; p += align256((size_t)(NB + 1) * 4);
    int* rowptr  = (int*)p; p += align256((size_t)(N + 1) * 4);
    int* csr_src = (int*)p; p += align256((size_t)(E + N) * 4);
    int* binned  = (int*)p; p += align256((size_t)E * 4);
    __half* h16 = (__half*)p; p += align256((size_t)N * 64 * 2);
    float* sA = (float*)p; p += align256((size_t)N * 4);
    float* dA = (float*)p; p += align256((size_t)N * 4);
    float* XA = (float*)p; p += align256((size_t)N * 64 * 4);
    float* XB = (float*)p; p += align256((size_t)N * 64 * 4);
    float* out = (float*)d_out;

    // ---- CSR build (two-level counting sort) ----
    int nchunk = (E + 4095) / 4096;
    hipMemsetAsync(gcnt, 0, (size_t)(NB + 1) * 4, stream);
    bucket_count_kernel<<<nchunk, 256, NB * 4, stream>>>(edst, gcnt, E, NB);
    bucket_scan_kernel<<<1, 512, 0, stream>>>(gcnt, boff, gfill, rowptr, NB, E, N);
    bucket_place_kernel<<<nchunk, 256, 2 * NB * 4, stream>>>(esrc, edst, gfill, binned, E, NB);
    bucket_build_kernel<<<NB, 256, 0, stream>>>(binned, boff, csr_src, rowptr, N);

    int tile_grid = (N + 63) / 64;
    int agg_grid  = (N + 3) / 4;

    // ---- layer 0: 128 -> 64, relu ----
    mfma_gemm_feat_kernel<128><<<tile_grid, 256, 0, stream>>>(x, W0, as0, ad0, h16, sA, dA, N);
    gat_aggregate_kernel<<<agg_grid, 256, 0, stream>>>(h16, sA, dA, rowptr, csr_src, b0, XA, N, 1);

    // ---- layer 1: 64 -> 64, relu ----
    mfma_gemm_feat_kernel<64><<<tile_grid, 256, 0, stream>>>(XA, W1, as1, ad1, h16, sA, dA, N);
    gat_aggregate_kernel<<<agg_grid, 256, 0, stream>>>(h16, sA, dA, rowptr, csr_src, b1, XB, N, 1);

    // ---- layer 2: 64 -> 64, no relu ----
    mfma_gemm_feat_kernel<64><<<tile_grid, 256, 0, stream>>>(XB, W2, as2, ad2, h16, sA, dA, N);
    gat_aggregate_kernel<<<agg_grid, 256, 0, stream>>>(h16, sA, dA, rowptr, csr_src, b2, out, N, 0);
}